// Round 4
// baseline (1328.466 us; speedup 1.0000x reference)
//
#include <hip/hip_runtime.h>

typedef unsigned short u16;
typedef unsigned int u32;
typedef __bf16 bf16x8 __attribute__((ext_vector_type(8)));
typedef float f32x4 __attribute__((ext_vector_type(4)));

#define NTOK 8192
#define CDIM 768
#define HDIM 3072
#define NEXP 8
#define NPAIR 16384

__device__ __forceinline__ float b2f(u16 u){ u32 v = ((u32)u)<<16; float f; __builtin_memcpy(&f,&v,4); return f; }
__device__ __forceinline__ u16 f2b(float f){ u32 u; __builtin_memcpy(&u,&f,4); u32 r = (u + 0x7FFF + ((u>>16)&1)) >> 16; return (u16)r; }
__device__ __forceinline__ int iclamp(int v,int lo,int hi){ return v<lo?lo:(v>hi?hi:v); }

// gelu via A&S 7.1.26 erf (|err|<=1.5e-7 — far below bf16 rounding)
__device__ __forceinline__ float gelu_f(float v){
  float x = fabsf(v)*0.70710678118654752f;
  float t = __builtin_amdgcn_rcpf(1.0f + 0.3275911f*x);
  float p = ((((1.061405429f*t - 1.453152027f)*t + 1.421413741f)*t - 0.284496736f)*t + 0.254829592f)*t;
  float er = 1.0f - p*__expf(-x*x);
  er = copysignf(er, v);
  return 0.5f*v*(1.0f+er);
}

// async 16B global->LDS: per-lane global addr OK; LDS dest = wave-uniform base + lane*16
__device__ __forceinline__ void gl2l16(const void* g, void* l){
  __builtin_amdgcn_global_load_lds((const __attribute__((address_space(1))) void*)g,
                                   (__attribute__((address_space(3))) void*)l, 16, 0, 0);
}

// raw barrier (no vmcnt drain) with compile-time memory fences: LDS/VMEM ops cannot cross
__device__ __forceinline__ void barf(){
  asm volatile("" ::: "memory");
  __builtin_amdgcn_s_barrier();
  asm volatile("" ::: "memory");
}
// pin register-only MFMA clusters inside their phase (rule #18: asm "memory" doesn't order them)
#define SBAR0() __builtin_amdgcn_sched_barrier(0)
#define WAITVM2() do{ asm volatile("s_waitcnt vmcnt(2)" ::: "memory"); SBAR0(); }while(0)
#define WAITVM0() do{ asm volatile("s_waitcnt vmcnt(0)" ::: "memory"); SBAR0(); }while(0)

// ---------------- dtype detect: fp32 viewed as u16 has garbage exponents ----------------
__global__ void detect_k(const u16* __restrict__ x, int* __restrict__ flagp){
  __shared__ int cnt;
  if (threadIdx.x==0) cnt=0;
  __syncthreads();
  int bad=0;
  for (int i=threadIdx.x; i<2048; i+=256){
    u16 u = x[i];
    int ex = (u>>7)&0xFF;
    if (ex >= 134) bad++;
  }
  if (bad) atomicAdd(&cnt, bad);
  __syncthreads();
  if (threadIdx.x==0) *flagp = (cnt > 32) ? 1 : 0;
}

// ---------------- convert (fp32->bf16) or copy (bf16), 4 elems/thread ----------------
__global__ __launch_bounds__(256) void conv_k(const void* __restrict__ src, u16* __restrict__ dst,
                                              int n4, const int* __restrict__ flagp){
  int i = blockIdx.x*256 + threadIdx.x;
  if (i >= n4) return;
  if (*flagp){
    float4 v = ((const float4*)src)[i];
    ushort4 o; o.x=f2b(v.x); o.y=f2b(v.y); o.z=f2b(v.z); o.w=f2b(v.w);
    ((ushort4*)dst)[i] = o;
  } else {
    ((ushort4*)dst)[i] = ((const ushort4*)src)[i];
  }
}

// ---------------- router: reads ORIGINAL inputs, fp64 exact logits ----------------
__global__ __launch_bounds__(256) void router_k(const void* __restrict__ xraw, const void* __restrict__ Wrraw,
    const int* __restrict__ flagp,
    int* __restrict__ tok_e, float* __restrict__ tok_w, int* __restrict__ counts){
  int fp32f = *flagp;
  int tok = blockIdx.x*4 + (threadIdx.x>>6);
  int lane = threadIdx.x & 63;
  double acc[8];
  #pragma unroll
  for(int e=0;e<8;e++) acc[e]=0.0;
  for(int j=0;j<12;j++){
    int c = j*64 + lane;
    if (fp32f){
      double xv = (double)((const float*)xraw)[(size_t)tok*CDIM + c];
      const float* wr = (const float*)Wrraw + (size_t)c*8;
      float4 w0 = *(const float4*)wr;
      float4 w1 = *(const float4*)(wr+4);
      acc[0] += xv*(double)w0.x; acc[1] += xv*(double)w0.y;
      acc[2] += xv*(double)w0.z; acc[3] += xv*(double)w0.w;
      acc[4] += xv*(double)w1.x; acc[5] += xv*(double)w1.y;
      acc[6] += xv*(double)w1.z; acc[7] += xv*(double)w1.w;
    } else {
      double xv = (double)b2f(((const u16*)xraw)[(size_t)tok*CDIM + c]);
      uint4 wv = *(const uint4*)((const u16*)Wrraw + (size_t)c*8);
      acc[0] += xv*(double)b2f((u16)(wv.x&0xFFFF));
      acc[1] += xv*(double)b2f((u16)(wv.x>>16));
      acc[2] += xv*(double)b2f((u16)(wv.y&0xFFFF));
      acc[3] += xv*(double)b2f((u16)(wv.y>>16));
      acc[4] += xv*(double)b2f((u16)(wv.z&0xFFFF));
      acc[5] += xv*(double)b2f((u16)(wv.z>>16));
      acc[6] += xv*(double)b2f((u16)(wv.w&0xFFFF));
      acc[7] += xv*(double)b2f((u16)(wv.w>>16));
    }
  }
  #pragma unroll
  for(int e=0;e<8;e++){
    #pragma unroll
    for(int off=32;off>0;off>>=1) acc[e] += __shfl_down(acc[e], off);
  }
  if (lane==0){
    int i0=0; double b0=acc[0];
    #pragma unroll
    for(int e=1;e<8;e++) if(acc[e]>b0){ b0=acc[e]; i0=e; }
    int i1=(i0+1)&7; double b1v=-1e300;
    #pragma unroll
    for(int e=0;e<8;e++) if(e!=i0 && acc[e]>b1v){ b1v=acc[e]; i1=e; }
    double Z = 0.0;
    #pragma unroll
    for(int e=0;e<8;e++) Z += exp(acc[e]-b0);
    double pr0 = 1.0/Z;
    double pr1 = exp(b1v-b0)/Z;
    double s = pr0+pr1+1e-9;
    tok_e[2*tok]=i0; tok_e[2*tok+1]=i1;
    tok_w[2*tok]=(float)(pr0/s); tok_w[2*tok+1]=(float)(pr1/s);
    atomicAdd(&counts[i0],1); atomicAdd(&counts[i1],1);
  }
}

// ---------------- counts -> offsets/cursors + utilization output ----------------
__global__ void offsets_k(const int* __restrict__ counts, int* __restrict__ offsets,
                          int* __restrict__ cursor, void* __restrict__ dout,
                          const int* __restrict__ flagp){
  if (threadIdx.x==0 && blockIdx.x==0){
    int fp32f = *flagp;
    int s=0, tot=0;
    for(int e=0;e<8;e++) tot += counts[e];
    for(int e=0;e<8;e++){ offsets[e]=s; cursor[e]=s; s+=counts[e]; }
    offsets[8]=s;
    float inv = 1.f/((float)tot + 1e-9f);
    for(int e=0;e<8;e++){
      float val = (float)counts[e]*inv;
      if (fp32f) ((float*)dout)[(size_t)NTOK*CDIM + e] = val;
      else       ((u16*)dout)[(size_t)NTOK*CDIM + e]   = f2b(val);
    }
  }
}

// ---------------- scatter tokens into per-expert segments (fully clamped) ----------------
__global__ __launch_bounds__(256) void scatter_k(const int* __restrict__ tok_e, int* __restrict__ cursor,
    int* __restrict__ pair_tok, int* __restrict__ tok_pos){
  int tkn = blockIdx.x*256 + threadIdx.x;
  if (tkn >= NTOK) return;
  #pragma unroll
  for(int j=0;j<2;j++){
    int e = tok_e[2*tkn+j] & 7;
    int p = atomicAdd(&cursor[e], 1);
    p = iclamp(p, 0, NPAIR-1);
    pair_tok[p] = tkn;
    tok_pos[2*tkn+j] = p;
  }
}

// ---------------- transpose per expert, fused dtype conversion ----------------
__global__ __launch_bounds__(256) void transpose_k(const void* __restrict__ inv, u16* __restrict__ out,
                                                   int R, int Cc, const int* __restrict__ flagp){
  __shared__ u16 T[64][65];
  int fp32f = *flagp;
  int ex = blockIdx.z;
  size_t base = (size_t)ex*R*Cc;
  out += base;
  int c0 = blockIdx.x*64, r0 = blockIdx.y*64;
  int tx = threadIdx.x & 31, ty = threadIdx.x >> 5;
  #pragma unroll
  for(int i=0;i<8;i++){
    int row = ty + i*8;
    size_t idx = base + (size_t)(r0+row)*Cc + c0 + tx*2;
    u32 v;
    if (fp32f){
      float2 f2v = *(const float2*)((const float*)inv + idx);
      v = (u32)f2b(f2v.x) | ((u32)f2b(f2v.y)<<16);
    } else {
      v = *(const u32*)((const u16*)inv + idx);
    }
    T[row][tx*2]   = (u16)(v&0xFFFF);
    T[row][tx*2+1] = (u16)(v>>16);
  }
  __syncthreads();
  #pragma unroll
  for(int i=0;i<8;i++){
    int row = ty + i*8;
    u32 lo = T[tx*2][row], hi = T[tx*2+1][row];
    *(u32*)(out + (size_t)(c0+row)*R + r0 + tx*2) = lo | (hi<<16);
  }
}

// ================= grouped GEMM: 256xBN tile, BK=64, 8-wave 8-phase counted-vmcnt =================
// T3+T4 schedule (m248 grouped 8ph=848 TF). Per K-tile, 4 phases of
//   { ds_read frag subtile ; issue 1 half-tile stage ; sched_barrier ; s_barrier ;
//     setprio(1) MFMA(16) setprio(0) ; sched_barrier ; s_barrier }.
// ONLY main-loop wait: vmcnt(2) at P3 (newest A0-half's 2 loads stay in flight across the
// barrier — never drain-to-0). Half-tile pipeline (A0,B0,A1,B1 halves):
//   stages: P0(t):(t+1).B0  P1(t):(t+1).A1  P2(t):(t+1).B1  P3(t):(t+2).A0
//   vacancy: tile t's B halves fully ds-read by end-P1(t); A halves by end-P2(t);
//   P3's stage of (t+2).A0 overwrites (t).A0 — safe, all reads completed before end-P2 barrier
//   (lgkm waits precede MFMAs; sched_barrier pins MFMAs before the phase-closing s_barrier).
// vmcnt audit at P3(t): outstanding = A0(t+1)[2] B0(t+1)[BI] A1(t+1)[2] B1(t+1)[BI] A0(t+2)[2];
//   vmcnt(2) -> everything of tile t+1 landed, only A0(t+2) in flight.  (BI = 2 or 1.)
// LDS: As[2][256][64] 64KB + Bs[2][BN_][64] (64/32KB). Chunk-XOR swizzle phys16B=logical^(row&7),
// pre-swizzled on the GLOBAL source (rule 21); ds_read_b128 conflict-free (0 measured R0/R1/R3).
// EPI 0: gelu(acc+bias)->bf16   EPI 1: acc+bias->fp32
#define BM2 256
#define BK2 64

template<int EPI, int BN_>
__global__ __launch_bounds__(512, 2) void gemm8_k(
    const u16* __restrict__ Abase, const int* __restrict__ pair_tok, int astride,
    const u16* __restrict__ Bt, const u16* __restrict__ bias,
    const int* __restrict__ offsets, int K, int N,
    u16* __restrict__ out_bf, float* __restrict__ out_f)
{
  constexpr int NF = BN_/64;        // N-frags per wave (4 or 2)
  constexpr int NS = NF/2;          // frags per B set (2 or 1)
  constexpr int BI = (BN_==256)?2:1;// gl2l16 issues per B half per wave
  constexpr int BH = BN_/2;         // rows per B half

  int e = blockIdx.z;
  int seg0 = iclamp(offsets[e],   0, NPAIR);
  int seg1 = iclamp(offsets[e+1], seg0, NPAIR);
  int Me = seg1 - seg0;
  int m0 = blockIdx.x * BM2;
  if (m0 >= Me) return;              // block-uniform: no divergent barriers
  int n0 = blockIdx.y * BN_;

  alignas(16) __shared__ u16 As[2][BM2][BK2];
  alignas(16) __shared__ u16 Bs[2][BN_][BK2];

  int t = threadIdx.x;
  int wave = t>>6, lane = t&63;
  int wr = wave>>2, wc = wave&3;
  int lr = lane&15, quad = lane>>4;

  // staging: one gl2l16 = 8 rows x 128B; lane row = srow8, phys chunk = lane&7,
  // sourced from logical chunk cl (pre-swizzle; LDS linear but logically chunk-XOR'd)
  int srow8 = lane>>3;
  int cl    = (lane&7) ^ srow8;
  const u16* bbase = Bt + (size_t)e*(size_t)N*K;

  const u16* aptrA[2][2];
  #pragma unroll
  for(int h=0;h<2;h++)
    #pragma unroll
    for(int i=0;i<2;i++){
      int tr = h*128 + wave*16 + i*8 + srow8;         // tile row 0..255
      int rr = iclamp(seg0 + m0 + tr, 0, seg1-1);
      int row = pair_tok ? iclamp(pair_tok[rr], 0, NTOK-1) : rr;
      aptrA[h][i] = Abase + (size_t)row*astride + cl*8;
    }
  const u16* bptrB[2][2];
  #pragma unroll
  for(int h=0;h<2;h++)
    #pragma unroll
    for(int i=0;i<BI;i++){
      int tr = h*BH + (BI==2 ? wave*16 + i*8 + srow8 : wave*8 + srow8);
      bptrB[h][i] = bbase + (size_t)(n0+tr)*K + cl*8;
    }

  auto STAGE_A = [&](int tt, int h){
    #pragma unroll
    for(int i=0;i<2;i++)
      gl2l16(aptrA[h][i] + (size_t)tt*64, &As[tt&1][h*128 + wave*16 + i*8][0]);
  };
  auto STAGE_B = [&](int tt, int h){
    #pragma unroll
    for(int i=0;i<BI;i++)
      gl2l16(bptrB[h][i] + (size_t)tt*64, &Bs[tt&1][h*BH + (BI==2 ? wave*16+i*8 : wave*8)][0]);
  };

  f32x4 acc[8][NF];
  #pragma unroll
  for(int i=0;i<8;i++)
    #pragma unroll
    for(int j=0;j<NF;j++) acc[i][j]=(f32x4){0.f,0.f,0.f,0.f};

  int nt = K/BK2;
  // prologue: tile0 fully + tile1.A0; keep tile1.A0 (2 loads) in flight
  STAGE_A(0,0); STAGE_B(0,0); STAGE_A(0,1); STAGE_B(0,1);
  if (nt>1){ STAGE_A(1,0); WAITVM2(); } else { WAITVM0(); }
  barf();

  bf16x8 af[4][2], bfv[NF][2];

  for(int kt=0; kt<nt; ++kt){
    int cb = kt&1;
    // ---- P0: read A set0 (rows wr*128+0..63) + B set0; stage (t+1).B0; MFMA set0 x Bset0
    #pragma unroll
    for(int i=0;i<4;i++){
      int r = wr*128 + i*16 + lr;
      #pragma unroll
      for(int ks=0;ks<2;ks++) af[i][ks] = *(const bf16x8*)&As[cb][r][((ks*4+quad) ^ (r&7))*8];
    }
    #pragma unroll
    for(int j=0;j<NS;j++){
      int r = wc*(BN_/4) + j*16 + lr;
      #pragma unroll
      for(int ks=0;ks<2;ks++) bfv[j][ks] = *(const bf16x8*)&Bs[cb][r][((ks*4+quad) ^ (r&7))*8];
    }
    if (kt+1<nt) STAGE_B(kt+1, 0);
    SBAR0(); barf();
    __builtin_amdgcn_s_setprio(1);
    #pragma unroll
    for(int ks=0;ks<2;ks++)
      #pragma unroll
      for(int i=0;i<4;i++)
        #pragma unroll
        for(int j=0;j<NS;j++)
          acc[i][j] = __builtin_amdgcn_mfma_f32_16x16x32_bf16(af[i][ks], bfv[j][ks], acc[i][j], 0,0,0);
    __builtin_amdgcn_s_setprio(0);
    SBAR0(); barf();
    // ---- P1: read B set1; stage (t+1).A1; MFMA set0 x Bset1
    #pragma unroll
    for(int j=NS;j<NF;j++){
      int r = wc*(BN_/4) + j*16 + lr;
      #pragma unroll
      for(int ks=0;ks<2;ks++) bfv[j][ks] = *(const bf16x8*)&Bs[cb][r][((ks*4+quad) ^ (r&7))*8];
    }
    if (kt+1<nt) STAGE_A(kt+1, 1);
    SBAR0(); barf();
    __builtin_amdgcn_s_setprio(1);
    #pragma unroll
    for(int ks=0;ks<2;ks++)
      #pragma unroll
      for(int i=0;i<4;i++)
        #pragma unroll
        for(int j=NS;j<NF;j++)
          acc[i][j] = __builtin_amdgcn_mfma_f32_16x16x32_bf16(af[i][ks], bfv[j][ks], acc[i][j], 0,0,0);
    __builtin_amdgcn_s_setprio(0);
    SBAR0(); barf();
    // ---- P2: read A set1 (rows wr*128+64..127, reuse af regs); stage (t+1).B1; MFMA set1 x Bset1
    #pragma unroll
    for(int i=0;i<4;i++){
      int r = wr*128 + (4+i)*16 + lr;
      #pragma unroll
      for(int ks=0;ks<2;ks++) af[i][ks] = *(const bf16x8*)&As[cb][r][((ks*4+quad) ^ (r&7))*8];
    }
    if (kt+1<nt) STAGE_B(kt+1, 1);
    SBAR0(); barf();
    __builtin_amdgcn_s_setprio(1);
    #pragma unroll
    for(int ks=0;ks<2;ks++)
      #pragma unroll
      for(int i=0;i<4;i++)
        #pragma unroll
        for(int j=NS;j<NF;j++)
          acc[4+i][j] = __builtin_amdgcn_mfma_f32_16x16x32_bf16(af[i][ks], bfv[j][ks], acc[4+i][j], 0,0,0);
    __builtin_amdgcn_s_setprio(0);
    SBAR0(); barf();
    // ---- P3: stage (t+2).A0 over vacated (t).A0; ONE counted wait/tile; MFMA set1 x Bset0
    if (kt+2<nt){ STAGE_A(kt+2, 0); WAITVM2(); }
    else if (kt+1<nt){ WAITVM0(); }
    SBAR0(); barf();
    __builtin_amdgcn_s_setprio(1);
    #pragma unroll
    for(int ks=0;ks<2;ks++)
      #pragma unroll
      for(int i=0;i<4;i++)
        #pragma unroll
        for(int j=0;j<NS;j++)
          acc[4+i][j] = __builtin_amdgcn_mfma_f32_16x16x32_bf16(af[i][ks], bfv[j][ks], acc[4+i][j], 0,0,0);
    __builtin_amdgcn_s_setprio(0);
    SBAR0(); barf();
  }

  // epilogue: D layout col=lane&15, row=quad*4+reg  [verified m89/m91]
  #pragma unroll
  for(int i=0;i<8;i++){
    int mm_base = wr*128 + i*16 + quad*4;
    #pragma unroll
    for(int j=0;j<NF;j++){
      int nn = n0 + wc*(BN_/4) + j*16 + lr;
      float bv = b2f(bias[(size_t)e*N + nn]);
      #pragma unroll
      for(int rg=0;rg<4;rg++){
        int mm = m0 + mm_base + rg;
        if (mm < Me){
          int r = seg0 + mm;
          float v = acc[i][j][rg] + bv;
          if (EPI==0) out_bf[(size_t)r*N + nn] = f2b(gelu_f(v));
          else        out_f[(size_t)r*N + nn] = v;
        }
      }
    }
  }
}

// ---------------- combine: out[tok] = w0*y[pos0] + w1*y[pos1] ----------------
__global__ __launch_bounds__(192) void combine_k(const float* __restrict__ y,
    const int* __restrict__ tok_pos, const float* __restrict__ tok_w,
    void* __restrict__ outv, const int* __restrict__ flagp){
  int fp32f = *flagp;
  int tkn = blockIdx.x;
  int c = threadIdx.x*4;
  int p0 = iclamp(tok_pos[2*tkn],   0, NPAIR-1);
  int p1 = iclamp(tok_pos[2*tkn+1], 0, NPAIR-1);
  float w0 = tok_w[2*tkn], w1 = tok_w[2*tkn+1];
  float4 a = *(const float4*)(y + (size_t)p0*CDIM + c);
  float4 b = *(const float4*)(y + (size_t)p1*CDIM + c);
  float4 o4;
  o4.x = w0*a.x + w1*b.x;
  o4.y = w0*a.y + w1*b.y;
  o4.z = w0*a.z + w1*b.z;
  o4.w = w0*a.w + w1*b.w;
  if (fp32f){
    *(float4*)((float*)outv + (size_t)tkn*CDIM + c) = o4;
  } else {
    ushort4 o;
    o.x = f2b(o4.x); o.y = f2b(o4.y); o.z = f2b(o4.z); o.w = f2b(o4.w);
    *(ushort4*)((u16*)outv + (size_t)tkn*CDIM + c) = o;
  }
}

extern "C" void kernel_launch(void* const* d_in, const int* in_sizes, int n_in,
                              void* d_out, int out_size, void* d_ws, size_t ws_size,
                              hipStream_t stream) {
  const void* x  = d_in[0];
  const void* Wr = d_in[1];
  const void* W1 = d_in[2];
  const void* b1 = d_in[3];
  const void* W2 = d_in[4];
  const void* b2 = d_in[5];

  // ws carve (all offsets multiple of 16)
  char* w = (char*)d_ws;
  int*   flagp    = (int*)w;                   // 1
  int*   counts   = (int*)(w + 256);           // 8
  int*   offsets  = (int*)(w + 512);           // 9
  int*   cursor   = (int*)(w + 768);           // 8
  int*   tok_e    = (int*)(w + 1024);          // 16384
  float* tok_w    = (float*)(w + 66560);       // 16384
  int*   tok_pos  = (int*)(w + 132096);        // 16384
  int*   pair_tok = (int*)(w + 197632);        // 16384
  u16*   b1c      = (u16*)(w + 263168);        // 24576 B
  u16*   b2c      = (u16*)(w + 312320);        // 6144 B
  u16*   xc       = (u16*)(w + 336896);        // 12582912 B
  u16*   W1t      = (u16*)(w + 12919808);      // [E][H][C] 37748736 B
  u16*   W2t      = W1t + (size_t)NEXP*CDIM*HDIM;      // [E][C][H] 37748736 B
  u16*   h        = W2t + (size_t)NEXP*CDIM*HDIM;      // [NPAIR][H] bf16
  float* y        = (float*)(h + (size_t)NPAIR*HDIM);  // [NPAIR][C] fp32
  size_t need = 189080576ull + (size_t)NPAIR*CDIM*4;   // ~239.4 MB
  if (ws_size < need) {
    hipMemsetAsync(d_out, 0, (size_t)out_size*2, stream);
    return;
  }

  hipMemsetAsync(counts, 0, 32, stream);
  detect_k<<<1, 256, 0, stream>>>((const u16*)x, flagp);
  conv_k<<<6144, 256, 0, stream>>>(x,  xc,  NTOK*CDIM/4, flagp);
  conv_k<<<24,   256, 0, stream>>>(b1, b1c, NEXP*HDIM/4, flagp);
  conv_k<<<6,    256, 0, stream>>>(b2, b2c, NEXP*CDIM/4, flagp);
  // W1 [E][C][H] -> W1t [E][H][C]; W2 [E][H][C] -> W2t [E][C][H]
  transpose_k<<<dim3(HDIM/64, CDIM/64, NEXP), 256, 0, stream>>>(W1, W1t, CDIM, HDIM, flagp);
  transpose_k<<<dim3(CDIM/64, HDIM/64, NEXP), 256, 0, stream>>>(W2, W2t, HDIM, CDIM, flagp);
  router_k<<<NTOK/4, 256, 0, stream>>>(x, Wr, flagp, tok_e, tok_w, counts);
  offsets_k<<<1, 64, 0, stream>>>(counts, offsets, cursor, d_out, flagp);
  scatter_k<<<NTOK/256, 256, 0, stream>>>(tok_e, cursor, pair_tok, tok_pos);
  // GEMM1: h = gelu(x_gathered @ W1[e] + b1[e])   [Me x 3072] bf16, 256x256 tiles
  gemm8_k<0,256><<<dim3(NTOK/BM2, HDIM/256, NEXP), 512, 0, stream>>>(
      xc, pair_tok, CDIM, W1t, b1c, offsets, CDIM, HDIM, h, nullptr);
  // GEMM2: y = h @ W2[e] + b2[e]                  [Me x 768] fp32, 256x128 tiles
  gemm8_k<1,128><<<dim3(NTOK/BM2, CDIM/128, NEXP), 512, 0, stream>>>(
      h, nullptr, HDIM, W2t, b2c, offsets, HDIM, CDIM, nullptr, y);
  combine_k<<<NTOK, 192, 0, stream>>>(y, tok_pos, tok_w, d_out, flagp);
}

// Round 5
// 755.542 us; speedup vs baseline: 1.7583x; 1.7583x over previous
//
#include <hip/hip_runtime.h>

typedef unsigned short u16;
typedef unsigned int u32;
typedef __bf16 bf16x8 __attribute__((ext_vector_type(8)));
typedef float f32x4 __attribute__((ext_vector_type(4)));

#define NTOK 8192
#define CDIM 768
#define HDIM 3072
#define NEXP 8
#define NPAIR 16384

__device__ __forceinline__ float b2f(u16 u){ u32 v = ((u32)u)<<16; float f; __builtin_memcpy(&f,&v,4); return f; }
__device__ __forceinline__ u16 f2b(float f){ u32 u; __builtin_memcpy(&u,&f,4); u32 r = (u + 0x7FFF + ((u>>16)&1)) >> 16; return (u16)r; }
__device__ __forceinline__ int iclamp(int v,int lo,int hi){ return v<lo?lo:(v>hi?hi:v); }

// gelu via A&S 7.1.26 erf (|err|<=1.5e-7 — far below bf16 rounding)
__device__ __forceinline__ float gelu_f(float v){
  float x = fabsf(v)*0.70710678118654752f;
  float t = __builtin_amdgcn_rcpf(1.0f + 0.3275911f*x);
  float p = ((((1.061405429f*t - 1.453152027f)*t + 1.421413741f)*t - 0.284496736f)*t + 0.254829592f)*t;
  float er = 1.0f - p*__expf(-x*x);
  er = copysignf(er, v);
  return 0.5f*v*(1.0f+er);
}

// async 16B global->LDS: per-lane global addr OK; LDS dest = wave-uniform base + lane*16
__device__ __forceinline__ void gl2l16(const void* g, void* l){
  __builtin_amdgcn_global_load_lds((const __attribute__((address_space(1))) void*)g,
                                   (__attribute__((address_space(3))) void*)l, 16, 0, 0);
}

// ---------------- dtype detect: fp32 viewed as u16 has garbage exponents ----------------
__global__ void detect_k(const u16* __restrict__ x, int* __restrict__ flagp){
  __shared__ int cnt;
  if (threadIdx.x==0) cnt=0;
  __syncthreads();
  int bad=0;
  for (int i=threadIdx.x; i<2048; i+=256){
    u16 u = x[i];
    int ex = (u>>7)&0xFF;
    if (ex >= 134) bad++;
  }
  if (bad) atomicAdd(&cnt, bad);
  __syncthreads();
  if (threadIdx.x==0) *flagp = (cnt > 32) ? 1 : 0;
}

// ---------------- convert (fp32->bf16) or copy (bf16), 4 elems/thread ----------------
__global__ __launch_bounds__(256) void conv_k(const void* __restrict__ src, u16* __restrict__ dst,
                                              int n4, const int* __restrict__ flagp){
  int i = blockIdx.x*256 + threadIdx.x;
  if (i >= n4) return;
  if (*flagp){
    float4 v = ((const float4*)src)[i];
    ushort4 o; o.x=f2b(v.x); o.y=f2b(v.y); o.z=f2b(v.z); o.w=f2b(v.w);
    ((ushort4*)dst)[i] = o;
  } else {
    ((ushort4*)dst)[i] = ((const ushort4*)src)[i];
  }
}

// ---------------- router: reads ORIGINAL inputs, fp64 exact logits ----------------
__global__ __launch_bounds__(256) void router_k(const void* __restrict__ xraw, const void* __restrict__ Wrraw,
    const int* __restrict__ flagp,
    int* __restrict__ tok_e, float* __restrict__ tok_w, int* __restrict__ counts){
  int fp32f = *flagp;
  int tok = blockIdx.x*4 + (threadIdx.x>>6);
  int lane = threadIdx.x & 63;
  double acc[8];
  #pragma unroll
  for(int e=0;e<8;e++) acc[e]=0.0;
  for(int j=0;j<12;j++){
    int c = j*64 + lane;
    if (fp32f){
      double xv = (double)((const float*)xraw)[(size_t)tok*CDIM + c];
      const float* wr = (const float*)Wrraw + (size_t)c*8;
      float4 w0 = *(const float4*)wr;
      float4 w1 = *(const float4*)(wr+4);
      acc[0] += xv*(double)w0.x; acc[1] += xv*(double)w0.y;
      acc[2] += xv*(double)w0.z; acc[3] += xv*(double)w0.w;
      acc[4] += xv*(double)w1.x; acc[5] += xv*(double)w1.y;
      acc[6] += xv*(double)w1.z; acc[7] += xv*(double)w1.w;
    } else {
      double xv = (double)b2f(((const u16*)xraw)[(size_t)tok*CDIM + c]);
      uint4 wv = *(const uint4*)((const u16*)Wrraw + (size_t)c*8);
      acc[0] += xv*(double)b2f((u16)(wv.x&0xFFFF));
      acc[1] += xv*(double)b2f((u16)(wv.x>>16));
      acc[2] += xv*(double)b2f((u16)(wv.y&0xFFFF));
      acc[3] += xv*(double)b2f((u16)(wv.y>>16));
      acc[4] += xv*(double)b2f((u16)(wv.z&0xFFFF));
      acc[5] += xv*(double)b2f((u16)(wv.z>>16));
      acc[6] += xv*(double)b2f((u16)(wv.w&0xFFFF));
      acc[7] += xv*(double)b2f((u16)(wv.w>>16));
    }
  }
  #pragma unroll
  for(int e=0;e<8;e++){
    #pragma unroll
    for(int off=32;off>0;off>>=1) acc[e] += __shfl_down(acc[e], off);
  }
  if (lane==0){
    int i0=0; double b0=acc[0];
    #pragma unroll
    for(int e=1;e<8;e++) if(acc[e]>b0){ b0=acc[e]; i0=e; }
    int i1=(i0+1)&7; double b1v=-1e300;
    #pragma unroll
    for(int e=0;e<8;e++) if(e!=i0 && acc[e]>b1v){ b1v=acc[e]; i1=e; }
    double Z = 0.0;
    #pragma unroll
    for(int e=0;e<8;e++) Z += exp(acc[e]-b0);
    double pr0 = 1.0/Z;
    double pr1 = exp(b1v-b0)/Z;
    double s = pr0+pr1+1e-9;
    tok_e[2*tok]=i0; tok_e[2*tok+1]=i1;
    tok_w[2*tok]=(float)(pr0/s); tok_w[2*tok+1]=(float)(pr1/s);
    atomicAdd(&counts[i0],1); atomicAdd(&counts[i1],1);
  }
}

// ---------------- counts -> offsets/cursors + utilization output ----------------
__global__ void offsets_k(const int* __restrict__ counts, int* __restrict__ offsets,
                          int* __restrict__ cursor, void* __restrict__ dout,
                          const int* __restrict__ flagp){
  if (threadIdx.x==0 && blockIdx.x==0){
    int fp32f = *flagp;
    int s=0, tot=0;
    for(int e=0;e<8;e++) tot += counts[e];
    for(int e=0;e<8;e++){ offsets[e]=s; cursor[e]=s; s+=counts[e]; }
    offsets[8]=s;
    float inv = 1.f/((float)tot + 1e-9f);
    for(int e=0;e<8;e++){
      float val = (float)counts[e]*inv;
      if (fp32f) ((float*)dout)[(size_t)NTOK*CDIM + e] = val;
      else       ((u16*)dout)[(size_t)NTOK*CDIM + e]   = f2b(val);
    }
  }
}

// ---------------- scatter tokens into per-expert segments (fully clamped) ----------------
__global__ __launch_bounds__(256) void scatter_k(const int* __restrict__ tok_e, int* __restrict__ cursor,
    int* __restrict__ pair_tok, int* __restrict__ tok_pos){
  int tkn = blockIdx.x*256 + threadIdx.x;
  if (tkn >= NTOK) return;
  #pragma unroll
  for(int j=0;j<2;j++){
    int e = tok_e[2*tkn+j] & 7;
    int p = atomicAdd(&cursor[e], 1);
    p = iclamp(p, 0, NPAIR-1);
    pair_tok[p] = tkn;
    tok_pos[2*tkn+j] = p;
  }
}

// ---------------- transpose per expert, fused dtype conversion ----------------
__global__ __launch_bounds__(256) void transpose_k(const void* __restrict__ inv, u16* __restrict__ out,
                                                   int R, int Cc, const int* __restrict__ flagp){
  __shared__ u16 T[64][65];
  int fp32f = *flagp;
  int ex = blockIdx.z;
  size_t base = (size_t)ex*R*Cc;
  out += base;
  int c0 = blockIdx.x*64, r0 = blockIdx.y*64;
  int tx = threadIdx.x & 31, ty = threadIdx.x >> 5;
  #pragma unroll
  for(int i=0;i<8;i++){
    int row = ty + i*8;
    size_t idx = base + (size_t)(r0+row)*Cc + c0 + tx*2;
    u32 v;
    if (fp32f){
      float2 f2v = *(const float2*)((const float*)inv + idx);
      v = (u32)f2b(f2v.x) | ((u32)f2b(f2v.y)<<16);
    } else {
      v = *(const u32*)((const u16*)inv + idx);
    }
    T[row][tx*2]   = (u16)(v&0xFFFF);
    T[row][tx*2+1] = (u16)(v>>16);
  }
  __syncthreads();
  #pragma unroll
  for(int i=0;i<8;i++){
    int row = ty + i*8;
    u32 lo = T[tx*2][row], hi = T[tx*2+1][row];
    *(u32*)(out + (size_t)(c0+row)*R + r0 + tx*2) = lo | (hi<<16);
  }
}

// ================= grouped GEMM: 128x128 tile, BK=64, 2-phase + XCD/L2-aware remap ==============
// Compute schedule = R1's verified 270us kernel, UNCHANGED (prefetch next tile's
// global_load_lds, ds_read current, MFMA, __syncthreads drain; 2 blocks/CU).
// NEW: block->work remap (T1/m204 bijective, nwg%8==0). The HW dispatches flat blockIdx
// round-robin across the 8 XCDs (j%8 = xcd); wid=(j%8)*q + j/8 gives each XCD a CONTIGUOUS
// work chunk. Work order is expert-major, then m-block outer / 3-n-block slab inner:
//   wid -> slab=wid/192, s=wid%192; e=slab/NSLABS_E; nslab=slab%NSLABS_E;
//   mb=s/3; ny=s%3; m0=mb*128; n0=(nslab*3+ny)*128.
// With chunk q = 192*NSLABS_E, XCD k processes EXACTLY expert k (both GEMMs):
//   per-XCD L2 resident set = 3 B panels (576 KB) + expert-k A rows (~3 MB) < 4 MB L2
//   -> B fetched from L3 once per expert (38 MB chip-wide vs ~600 MB round-robin),
//      A rows stay L2-hot for the whole expert. Converts the measured ~4.4 TB/s L3-bound
//      staging stream (R0/R1 ceiling) into L2 hits.
// LDS chunk-XOR swizzle phys16B = logical^(row&7) pre-swizzled on the GLOBAL source
// (rule 21); ds_read_b128 conflict-free (0 conflicts measured R0/R1/R3/R4).
// EPI 0: gelu(acc+bias)->bf16   EPI 1: acc+bias->fp32
#define BM 128
#define BN 128
#define BK 64

template<int EPI, int NSLABS_E>
__global__ __launch_bounds__(256) void gemm_k(
    const u16* __restrict__ Abase, const int* __restrict__ pair_tok, int astride,
    const u16* __restrict__ Bt, const u16* __restrict__ bias,
    const int* __restrict__ offsets, int K, int N,
    u16* __restrict__ out_bf, float* __restrict__ out_f)
{
  // ---- XCD-binding decode (nwg = 64*3*NSLABS_E*8; q = nwg/8 = 192*NSLABS_E) ----
  constexpr int Q = 192*NSLABS_E;
  int j = blockIdx.x;
  int wid = (j&7)*Q + (j>>3);
  int slab = wid/192, s = wid - slab*192;
  int e  = slab / NSLABS_E;
  int ns = slab - e*NSLABS_E;
  int mb = s/3;
  int ny = s - mb*3;
  int m0 = mb*BM;
  int n0 = (ns*3 + ny)*BN;

  int seg0 = iclamp(offsets[e],   0, NPAIR);
  int seg1 = iclamp(offsets[e+1], seg0, NPAIR);
  int Me = seg1 - seg0;
  if (m0 >= Me) return;

  alignas(16) __shared__ u16 As[2*BM*BK];   // 32 KB
  alignas(16) __shared__ u16 Bs[2*BM*BK];   // 32 KB

  int t = threadIdx.x;
  int wave = t>>6, lane = t&63;
  int wm = (wave>>1)*64, wn = (wave&1)*64;
  int lr = lane&15, quad = lane>>4;

  // staging: one gl2l16 = 64 lanes x 16B = 8 rows x 128B. lane row = srow, phys chunk = lane&7,
  // sourced from logical chunk cl so LDS stays linear but is logically chunk-XOR swizzled.
  int srow = lane>>3;
  int cl   = (lane&7) ^ srow;
  const u16* aptr[4]; const u16* bptr[4];
  int lbase[4];
  const u16* bbase = Bt + (size_t)e*(size_t)N*K;
  #pragma unroll
  for(int i=0;i<4;i++){
    int tr = wave*32 + i*8 + srow;                 // tile-local row 0..127
    int rr = iclamp(seg0 + m0 + tr, 0, seg1-1);
    int row = pair_tok ? iclamp(pair_tok[rr], 0, NTOK-1) : rr;
    aptr[i] = Abase + (size_t)row*astride + cl*8;
    bptr[i] = bbase + (size_t)(n0+tr)*K + cl*8;
    lbase[i] = (wave*32 + i*8)*BK;                 // wave-uniform LDS base (u16 units)
  }

  f32x4 acc[4][4];
  #pragma unroll
  for(int i=0;i<4;i++)
    #pragma unroll
    for(int jj=0;jj<4;jj++) acc[i][jj]=(f32x4){0.f,0.f,0.f,0.f};

  // prologue: stage K-tile 0 into buffer 0
  #pragma unroll
  for(int i=0;i<4;i++){ gl2l16(aptr[i], &As[lbase[i]]); gl2l16(bptr[i], &Bs[lbase[i]]); }
  __syncthreads();   // vmcnt(0) drain + barrier: tile 0 resident

  int nt = K/BK;
  int cb = 0;                                      // current buffer offset (0 or BM*BK)
  for(int kt=0; kt<nt; ++kt){
    // issue next tile's loads FIRST — they fly under this tile's compute
    if (kt+1 < nt){
      int k0 = (kt+1)*BK;
      int nb = cb ^ (BM*BK);
      #pragma unroll
      for(int i=0;i<4;i++){ gl2l16(aptr[i]+k0, &As[nb+lbase[i]]); gl2l16(bptr[i]+k0, &Bs[nb+lbase[i]]); }
    }
    // ds_read fragments from current buffer (compiler emits fine-grained lgkmcnt before MFMA)
    bf16x8 af[4][2], bfr[4][2];
    #pragma unroll
    for(int i=0;i<4;i++){
      int ra = wm+i*16+lr;
      int rb = wn+i*16+lr;
      #pragma unroll
      for(int ks=0;ks<2;ks++){
        af[i][ks]  = *(const bf16x8*)(&As[cb + ra*BK + ((ks*4+quad) ^ (ra&7))*8]);
        bfr[i][ks] = *(const bf16x8*)(&Bs[cb + rb*BK + ((ks*4+quad) ^ (rb&7))*8]);
      }
    }
    #pragma unroll
    for(int ks=0;ks<2;ks++)
      #pragma unroll
      for(int i=0;i<4;i++)
        #pragma unroll
        for(int jj=0;jj<4;jj++)
          acc[i][jj] = __builtin_amdgcn_mfma_f32_16x16x32_bf16(af[i][ks], bfr[jj][ks], acc[i][jj], 0,0,0);
    __syncthreads();   // drains staging (vmcnt0) + fences buffer reuse
    cb ^= (BM*BK);
  }

  // epilogue: D layout col=lane&15, row=quad*4+reg  [verified m89/m91]
  #pragma unroll
  for(int i=0;i<4;i++){
    int mm_base = wm + i*16 + quad*4;
    #pragma unroll
    for(int jj=0;jj<4;jj++){
      int nn = n0 + wn + jj*16 + lr;
      float bv = b2f(bias[(size_t)e*N + nn]);
      #pragma unroll
      for(int rg=0;rg<4;rg++){
        int mm = m0 + mm_base + rg;
        if (mm < Me){
          int r = seg0 + mm;
          float v = acc[i][jj][rg] + bv;
          if (EPI==0) out_bf[(size_t)r*N + nn] = f2b(gelu_f(v));
          else        out_f[(size_t)r*N + nn] = v;
        }
      }
    }
  }
}

// ---------------- combine: out[tok] = w0*y[pos0] + w1*y[pos1] ----------------
__global__ __launch_bounds__(192) void combine_k(const float* __restrict__ y,
    const int* __restrict__ tok_pos, const float* __restrict__ tok_w,
    void* __restrict__ outv, const int* __restrict__ flagp){
  int fp32f = *flagp;
  int tkn = blockIdx.x;
  int c = threadIdx.x*4;
  int p0 = iclamp(tok_pos[2*tkn],   0, NPAIR-1);
  int p1 = iclamp(tok_pos[2*tkn+1], 0, NPAIR-1);
  float w0 = tok_w[2*tkn], w1 = tok_w[2*tkn+1];
  float4 a = *(const float4*)(y + (size_t)p0*CDIM + c);
  float4 b = *(const float4*)(y + (size_t)p1*CDIM + c);
  float4 o4;
  o4.x = w0*a.x + w1*b.x;
  o4.y = w0*a.y + w1*b.y;
  o4.z = w0*a.z + w1*b.z;
  o4.w = w0*a.w + w1*b.w;
  if (fp32f){
    *(float4*)((float*)outv + (size_t)tkn*CDIM + c) = o4;
  } else {
    ushort4 o;
    o.x = f2b(o4.x); o.y = f2b(o4.y); o.z = f2b(o4.z); o.w = f2b(o4.w);
    *(ushort4*)((u16*)outv + (size_t)tkn*CDIM + c) = o;
  }
}

extern "C" void kernel_launch(void* const* d_in, const int* in_sizes, int n_in,
                              void* d_out, int out_size, void* d_ws, size_t ws_size,
                              hipStream_t stream) {
  const void* x  = d_in[0];
  const void* Wr = d_in[1];
  const void* W1 = d_in[2];
  const void* b1 = d_in[3];
  const void* W2 = d_in[4];
  const void* b2 = d_in[5];

  // ws carve (all offsets multiple of 16)
  char* w = (char*)d_ws;
  int*   flagp    = (int*)w;                   // 1
  int*   counts   = (int*)(w + 256);           // 8
  int*   offsets  = (int*)(w + 512);           // 9
  int*   cursor   = (int*)(w + 768);           // 8
  int*   tok_e    = (int*)(w + 1024);          // 16384
  float* tok_w    = (float*)(w + 66560);       // 16384
  int*   tok_pos  = (int*)(w + 132096);        // 16384
  int*   pair_tok = (int*)(w + 197632);        // 16384
  u16*   b1c      = (u16*)(w + 263168);        // 24576 B
  u16*   b2c      = (u16*)(w + 312320);        // 6144 B
  u16*   xc       = (u16*)(w + 336896);        // 12582912 B
  u16*   W1t      = (u16*)(w + 12919808);      // [E][H][C] 37748736 B
  u16*   W2t      = W1t + (size_t)NEXP*CDIM*HDIM;      // [E][C][H] 37748736 B
  u16*   h        = W2t + (size_t)NEXP*CDIM*HDIM;      // [NPAIR][H] bf16
  float* y        = (float*)(h + (size_t)NPAIR*HDIM);  // [NPAIR][C] fp32
  size_t need = 189080576ull + (size_t)NPAIR*CDIM*4;   // ~239.4 MB
  if (ws_size < need) {
    hipMemsetAsync(d_out, 0, (size_t)out_size*2, stream);
    return;
  }

  hipMemsetAsync(counts, 0, 32, stream);
  detect_k<<<1, 256, 0, stream>>>((const u16*)x, flagp);
  conv_k<<<6144, 256, 0, stream>>>(x,  xc,  NTOK*CDIM/4, flagp);
  conv_k<<<24,   256, 0, stream>>>(b1, b1c, NEXP*HDIM/4, flagp);
  conv_k<<<6,    256, 0, stream>>>(b2, b2c, NEXP*CDIM/4, flagp);
  // W1 [E][C][H] -> W1t [E][H][C]; W2 [E][H][C] -> W2t [E][C][H]
  transpose_k<<<dim3(HDIM/64, CDIM/64, NEXP), 256, 0, stream>>>(W1, W1t, CDIM, HDIM, flagp);
  transpose_k<<<dim3(CDIM/64, HDIM/64, NEXP), 256, 0, stream>>>(W2, W2t, HDIM, CDIM, flagp);
  router_k<<<NTOK/4, 256, 0, stream>>>(x, Wr, flagp, tok_e, tok_w, counts);
  offsets_k<<<1, 64, 0, stream>>>(counts, offsets, cursor, d_out, flagp);
  scatter_k<<<NTOK/256, 256, 0, stream>>>(tok_e, cursor, pair_tok, tok_pos);
  // GEMM1: h = gelu(x_gathered @ W1[e] + b1[e])   [Me x 3072] bf16
  //   nwg = 64 m-blocks * 24 n-blocks * 8 experts = 12288 (NSLABS_E = 24/3 = 8)
  gemm_k<0,8><<<12288, 256, 0, stream>>>(
      xc, pair_tok, CDIM, W1t, b1c, offsets, CDIM, HDIM, h, nullptr);
  // GEMM2: y = h @ W2[e] + b2[e]                  [Me x 768] fp32
  //   nwg = 64 m-blocks * 6 n-blocks * 8 experts = 3072 (NSLABS_E = 6/3 = 2)
  gemm_k<1,2><<<3072, 256, 0, stream>>>(
      h, nullptr, HDIM, W2t, b2c, offsets, HDIM, CDIM, nullptr, y);
  combine_k<<<NTOK, 192, 0, stream>>>(y, tok_pos, tok_w, d_out, flagp);
}

// Round 6
// 512.993 us; speedup vs baseline: 2.5896x; 1.4728x over previous
//
#include <hip/hip_runtime.h>

typedef unsigned short u16;
typedef unsigned int u32;
typedef __bf16 bf16x8 __attribute__((ext_vector_type(8)));
typedef float f32x4 __attribute__((ext_vector_type(4)));

#define NTOK 8192
#define CDIM 768
#define HDIM 3072
#define NEXP 8
#define NPAIR 16384
#define HB 32   // hist/scatter blocks: HB*512 = NPAIR entries

__device__ __forceinline__ float b2f(u16 u){ u32 v = ((u32)u)<<16; float f; __builtin_memcpy(&f,&v,4); return f; }
__device__ __forceinline__ u16 f2b(float f){ u32 u; __builtin_memcpy(&u,&f,4); u32 r = (u + 0x7FFF + ((u>>16)&1)) >> 16; return (u16)r; }
__device__ __forceinline__ int iclamp(int v,int lo,int hi){ return v<lo?lo:(v>hi?hi:v); }

// gelu via A&S 7.1.26 erf (|err|<=1.5e-7 — far below bf16 rounding)
__device__ __forceinline__ float gelu_f(float v){
  float x = fabsf(v)*0.70710678118654752f;
  float t = __builtin_amdgcn_rcpf(1.0f + 0.3275911f*x);
  float p = ((((1.061405429f*t - 1.453152027f)*t + 1.421413741f)*t - 0.284496736f)*t + 0.254829592f)*t;
  float er = 1.0f - p*__expf(-x*x);
  er = copysignf(er, v);
  return 0.5f*v*(1.0f+er);
}

// async 16B global->LDS: per-lane global addr OK; LDS dest = wave-uniform base + lane*16
__device__ __forceinline__ void gl2l16(const void* g, void* l){
  __builtin_amdgcn_global_load_lds((const __attribute__((address_space(1))) void*)g,
                                   (__attribute__((address_space(3))) void*)l, 16, 0, 0);
}

// ---------------- dtype detect: fp32 viewed as u16 has garbage exponents ----------------
__global__ void detect_k(const u16* __restrict__ x, int* __restrict__ flagp){
  __shared__ int cnt;
  if (threadIdx.x==0) cnt=0;
  __syncthreads();
  int bad=0;
  for (int i=threadIdx.x; i<2048; i+=256){
    u16 u = x[i];
    int ex = (u>>7)&0xFF;
    if (ex >= 134) bad++;
  }
  if (bad) atomicAdd(&cnt, bad);
  __syncthreads();
  if (threadIdx.x==0) *flagp = (cnt > 32) ? 1 : 0;
}

// ---------------- convert (fp32->bf16) or copy (bf16), 4 elems/thread ----------------
__global__ __launch_bounds__(256) void conv_k(const void* __restrict__ src, u16* __restrict__ dst,
                                              int n4, const int* __restrict__ flagp){
  int i = blockIdx.x*256 + threadIdx.x;
  if (i >= n4) return;
  if (*flagp){
    float4 v = ((const float4*)src)[i];
    ushort4 o; o.x=f2b(v.x); o.y=f2b(v.y); o.z=f2b(v.z); o.w=f2b(v.w);
    ((ushort4*)dst)[i] = o;
  } else {
    ((ushort4*)dst)[i] = ((const ushort4*)src)[i];
  }
}

// ---------------- router: fp64-exact logits; NO ATOMICS (hist_k counts separately) ----------------
__global__ __launch_bounds__(256) void router_k(const void* __restrict__ xraw, const void* __restrict__ Wrraw,
    const int* __restrict__ flagp,
    int* __restrict__ tok_e, float* __restrict__ tok_w){
  int fp32f = *flagp;
  int tok = blockIdx.x*4 + (threadIdx.x>>6);
  int lane = threadIdx.x & 63;
  double acc[8];
  #pragma unroll
  for(int e=0;e<8;e++) acc[e]=0.0;
  for(int j=0;j<12;j++){
    int c = j*64 + lane;
    if (fp32f){
      double xv = (double)((const float*)xraw)[(size_t)tok*CDIM + c];
      const float* wr = (const float*)Wrraw + (size_t)c*8;
      float4 w0 = *(const float4*)wr;
      float4 w1 = *(const float4*)(wr+4);
      acc[0] += xv*(double)w0.x; acc[1] += xv*(double)w0.y;
      acc[2] += xv*(double)w0.z; acc[3] += xv*(double)w0.w;
      acc[4] += xv*(double)w1.x; acc[5] += xv*(double)w1.y;
      acc[6] += xv*(double)w1.z; acc[7] += xv*(double)w1.w;
    } else {
      double xv = (double)b2f(((const u16*)xraw)[(size_t)tok*CDIM + c]);
      uint4 wv = *(const uint4*)((const u16*)Wrraw + (size_t)c*8);
      acc[0] += xv*(double)b2f((u16)(wv.x&0xFFFF));
      acc[1] += xv*(double)b2f((u16)(wv.x>>16));
      acc[2] += xv*(double)b2f((u16)(wv.y&0xFFFF));
      acc[3] += xv*(double)b2f((u16)(wv.y>>16));
      acc[4] += xv*(double)b2f((u16)(wv.z&0xFFFF));
      acc[5] += xv*(double)b2f((u16)(wv.z>>16));
      acc[6] += xv*(double)b2f((u16)(wv.w&0xFFFF));
      acc[7] += xv*(double)b2f((u16)(wv.w>>16));
    }
  }
  #pragma unroll
  for(int e=0;e<8;e++){
    #pragma unroll
    for(int off=32;off>0;off>>=1) acc[e] += __shfl_down(acc[e], off);
  }
  if (lane==0){
    int i0=0; double b0=acc[0];
    #pragma unroll
    for(int e=1;e<8;e++) if(acc[e]>b0){ b0=acc[e]; i0=e; }
    int i1=(i0+1)&7; double b1v=-1e300;
    #pragma unroll
    for(int e=0;e<8;e++) if(e!=i0 && acc[e]>b1v){ b1v=acc[e]; i1=e; }
    double Z = 0.0;
    #pragma unroll
    for(int e=0;e<8;e++) Z += exp(acc[e]-b0);
    double pr0 = 1.0/Z;
    double pr1 = exp(b1v-b0)/Z;
    double s = pr0+pr1+1e-9;
    tok_e[2*tok]=i0; tok_e[2*tok+1]=i1;
    tok_w[2*tok]=(float)(pr0/s); tok_w[2*tok+1]=(float)(pr1/s);
  }
}

// ---------------- per-block expert histograms via ballot (zero atomics) ----------------
// entry index i in [0,NPAIR): i = 2*tkn + slot.  Block b covers [b*512, b*512+512).
__global__ __launch_bounds__(256) void hist_k(const int* __restrict__ tok_e, int* __restrict__ bhist){
  int b = blockIdx.x, t = threadIdx.x;
  int wave = t>>6, lane = t&63;
  __shared__ int lh[4][8];
  int base = b*512 + wave*128 + lane;
  int e0 = tok_e[base]    & 7;
  int e1 = tok_e[base+64] & 7;
  #pragma unroll
  for(int e=0;e<8;e++){
    unsigned long long m0 = __ballot(e0==e);
    unsigned long long m1 = __ballot(e1==e);
    if (lane==0) lh[wave][e] = __popcll(m0) + __popcll(m1);
  }
  __syncthreads();
  if (t<8){
    int s=0;
    #pragma unroll
    for(int w=0;w<4;w++) s += lh[w][t];
    bhist[b*8+t] = s;
  }
}

// ---------------- scan: bhist -> offsets[9], per-block bases, utilization output ----------------
__global__ __launch_bounds__(64) void offsets2_k(const int* __restrict__ bhist, int* __restrict__ offsets,
                          int* __restrict__ bbase, void* __restrict__ dout, const int* __restrict__ flagp){
  __shared__ int cnt[8], off[8];
  int t = threadIdx.x;
  if (t<8){
    int s=0;
    for(int b=0;b<HB;b++) s += bhist[b*8+t];
    cnt[t]=s;
  }
  __syncthreads();
  if (t==0){
    int s=0;
    for(int e=0;e<8;e++){ off[e]=s; offsets[e]=s; s+=cnt[e]; }
    offsets[8]=s;
    int fp32f = *flagp;
    float inv = 1.f/((float)s + 1e-9f);
    for(int e=0;e<8;e++){
      float val = (float)cnt[e]*inv;
      if (fp32f) ((float*)dout)[(size_t)NTOK*CDIM + e] = val;
      else       ((u16*)dout)[(size_t)NTOK*CDIM + e]   = f2b(val);
    }
  }
  __syncthreads();
  if (t<8){
    int a = off[t];
    for(int b=0;b<HB;b++){ bbase[b*8+t] = a; a += bhist[b*8+t]; }
  }
}

// ---------------- deterministic scatter: rank = block base + wave prefix + intra-wave rank ----------------
__global__ __launch_bounds__(256) void scatter2_k(const int* __restrict__ tok_e,
    const int* __restrict__ bbase, int* __restrict__ pair_tok, int* __restrict__ tok_pos){
  int b = blockIdx.x, t = threadIdx.x;
  int wave = t>>6, lane = t&63;
  __shared__ int lh[4][8];
  int base = b*512 + wave*128 + lane;
  int i0 = base, i1 = base+64;
  int e0 = tok_e[i0] & 7;
  int e1 = tok_e[i1] & 7;
  unsigned long long lt = (1ULL<<lane)-1;
  int r0=0, r1=0;
  #pragma unroll
  for(int e=0;e<8;e++){
    unsigned long long m0 = __ballot(e0==e);
    unsigned long long m1 = __ballot(e1==e);
    if (lane==0) lh[wave][e] = __popcll(m0) + __popcll(m1);
    if (e0==e) r0 = __popcll(m0 & lt);
    if (e1==e) r1 = __popcll(m0) + __popcll(m1 & lt);
  }
  __syncthreads();
  int wb0=0, wb1=0;
  for(int w=0;w<wave;w++){ wb0 += lh[w][e0]; wb1 += lh[w][e1]; }
  int p0 = iclamp(bbase[b*8+e0] + wb0 + r0, 0, NPAIR-1);
  int p1 = iclamp(bbase[b*8+e1] + wb1 + r1, 0, NPAIR-1);
  pair_tok[p0] = i0>>1;
  pair_tok[p1] = i1>>1;
  tok_pos[i0] = p0;
  tok_pos[i1] = p1;
}

// ---------------- transpose per expert, fused dtype conversion ----------------
__global__ __launch_bounds__(256) void transpose_k(const void* __restrict__ inv, u16* __restrict__ out,
                                                   int R, int Cc, const int* __restrict__ flagp){
  __shared__ u16 T[64][65];
  int fp32f = *flagp;
  int ex = blockIdx.z;
  size_t base = (size_t)ex*R*Cc;
  out += base;
  int c0 = blockIdx.x*64, r0 = blockIdx.y*64;
  int tx = threadIdx.x & 31, ty = threadIdx.x >> 5;
  #pragma unroll
  for(int i=0;i<8;i++){
    int row = ty + i*8;
    size_t idx = base + (size_t)(r0+row)*Cc + c0 + tx*2;
    u32 v;
    if (fp32f){
      float2 f2v = *(const float2*)((const float*)inv + idx);
      v = (u32)f2b(f2v.x) | ((u32)f2b(f2v.y)<<16);
    } else {
      v = *(const u32*)((const u16*)inv + idx);
    }
    T[row][tx*2]   = (u16)(v&0xFFFF);
    T[row][tx*2+1] = (u16)(v>>16);
  }
  __syncthreads();
  #pragma unroll
  for(int i=0;i<8;i++){
    int row = ty + i*8;
    u32 lo = T[tx*2][row], hi = T[tx*2+1][row];
    *(u32*)(out + (size_t)(c0+row)*R + r0 + tx*2) = lo | (hi<<16);
  }
}

// ================= grouped GEMM: 128x128 tile, BK=64, 2-phase + XCD/L2-aware remap ==============
// (R5 winner — UNCHANGED.) Block->work remap binds XCD k to expert k so B panels and the
// expert's gathered A rows stay resident in that XCD's 4 MB L2; staging comes from L2
// instead of the ~4.4 TB/s chip-wide L3 path that capped R0/R1.
//   wid=(j%8)*Q + j/8; slab=wid/192; s=wid%192; e=slab/NSLABS_E; ns=slab%NSLABS_E;
//   mb=s/3; ny=s%3; m0=mb*128; n0=(ns*3+ny)*128.
// LDS chunk-XOR swizzle phys16B = logical^(row&7) pre-swizzled on the GLOBAL source
// (rule 21); ds_read_b128 conflict-free (0 conflicts measured every round).
// EPI 0: gelu(acc+bias)->bf16   EPI 1: acc+bias->fp32
#define BM 128
#define BN 128
#define BK 64

template<int EPI, int NSLABS_E>
__global__ __launch_bounds__(256) void gemm_k(
    const u16* __restrict__ Abase, const int* __restrict__ pair_tok, int astride,
    const u16* __restrict__ Bt, const u16* __restrict__ bias,
    const int* __restrict__ offsets, int K, int N,
    u16* __restrict__ out_bf, float* __restrict__ out_f)
{
  constexpr int Q = 192*NSLABS_E;
  int j = blockIdx.x;
  int wid = (j&7)*Q + (j>>3);
  int slab = wid/192, s = wid - slab*192;
  int e  = slab / NSLABS_E;
  int ns = slab - e*NSLABS_E;
  int mb = s/3;
  int ny = s - mb*3;
  int m0 = mb*BM;
  int n0 = (ns*3 + ny)*BN;

  int seg0 = iclamp(offsets[e],   0, NPAIR);
  int seg1 = iclamp(offsets[e+1], seg0, NPAIR);
  int Me = seg1 - seg0;
  if (m0 >= Me) return;

  alignas(16) __shared__ u16 As[2*BM*BK];   // 32 KB
  alignas(16) __shared__ u16 Bs[2*BM*BK];   // 32 KB

  int t = threadIdx.x;
  int wave = t>>6, lane = t&63;
  int wm = (wave>>1)*64, wn = (wave&1)*64;
  int lr = lane&15, quad = lane>>4;

  int srow = lane>>3;
  int cl   = (lane&7) ^ srow;
  const u16* aptr[4]; const u16* bptr[4];
  int lbase[4];
  const u16* bbase_ = Bt + (size_t)e*(size_t)N*K;
  #pragma unroll
  for(int i=0;i<4;i++){
    int tr = wave*32 + i*8 + srow;                 // tile-local row 0..127
    int rr = iclamp(seg0 + m0 + tr, 0, seg1-1);
    int row = pair_tok ? iclamp(pair_tok[rr], 0, NTOK-1) : rr;
    aptr[i] = Abase + (size_t)row*astride + cl*8;
    bptr[i] = bbase_ + (size_t)(n0+tr)*K + cl*8;
    lbase[i] = (wave*32 + i*8)*BK;                 // wave-uniform LDS base (u16 units)
  }

  f32x4 acc[4][4];
  #pragma unroll
  for(int i=0;i<4;i++)
    #pragma unroll
    for(int jj=0;jj<4;jj++) acc[i][jj]=(f32x4){0.f,0.f,0.f,0.f};

  #pragma unroll
  for(int i=0;i<4;i++){ gl2l16(aptr[i], &As[lbase[i]]); gl2l16(bptr[i], &Bs[lbase[i]]); }
  __syncthreads();   // vmcnt(0) drain + barrier: tile 0 resident

  int nt = K/BK;
  int cb = 0;
  for(int kt=0; kt<nt; ++kt){
    if (kt+1 < nt){
      int k0 = (kt+1)*BK;
      int nb = cb ^ (BM*BK);
      #pragma unroll
      for(int i=0;i<4;i++){ gl2l16(aptr[i]+k0, &As[nb+lbase[i]]); gl2l16(bptr[i]+k0, &Bs[nb+lbase[i]]); }
    }
    bf16x8 af[4][2], bfr[4][2];
    #pragma unroll
    for(int i=0;i<4;i++){
      int ra = wm+i*16+lr;
      int rb = wn+i*16+lr;
      #pragma unroll
      for(int ks=0;ks<2;ks++){
        af[i][ks]  = *(const bf16x8*)(&As[cb + ra*BK + ((ks*4+quad) ^ (ra&7))*8]);
        bfr[i][ks] = *(const bf16x8*)(&Bs[cb + rb*BK + ((ks*4+quad) ^ (rb&7))*8]);
      }
    }
    #pragma unroll
    for(int ks=0;ks<2;ks++)
      #pragma unroll
      for(int i=0;i<4;i++)
        #pragma unroll
        for(int jj=0;jj<4;jj++)
          acc[i][jj] = __builtin_amdgcn_mfma_f32_16x16x32_bf16(af[i][ks], bfr[jj][ks], acc[i][jj], 0,0,0);
    __syncthreads();
    cb ^= (BM*BK);
  }

  // epilogue: D layout col=lane&15, row=quad*4+reg  [verified m89/m91]
  #pragma unroll
  for(int i=0;i<4;i++){
    int mm_base = wm + i*16 + quad*4;
    #pragma unroll
    for(int jj=0;jj<4;jj++){
      int nn = n0 + wn + jj*16 + lr;
      float bv = b2f(bias[(size_t)e*N + nn]);
      #pragma unroll
      for(int rg=0;rg<4;rg++){
        int mm = m0 + mm_base + rg;
        if (mm < Me){
          int r = seg0 + mm;
          float v = acc[i][jj][rg] + bv;
          if (EPI==0) out_bf[(size_t)r*N + nn] = f2b(gelu_f(v));
          else        out_f[(size_t)r*N + nn] = v;
        }
      }
    }
  }
}

// ---------------- combine: out[tok] = w0*y[pos0] + w1*y[pos1] ----------------
__global__ __launch_bounds__(192) void combine_k(const float* __restrict__ y,
    const int* __restrict__ tok_pos, const float* __restrict__ tok_w,
    void* __restrict__ outv, const int* __restrict__ flagp){
  int fp32f = *flagp;
  int tkn = blockIdx.x;
  int c = threadIdx.x*4;
  int p0 = iclamp(tok_pos[2*tkn],   0, NPAIR-1);
  int p1 = iclamp(tok_pos[2*tkn+1], 0, NPAIR-1);
  float w0 = tok_w[2*tkn], w1 = tok_w[2*tkn+1];
  float4 a = *(const float4*)(y + (size_t)p0*CDIM + c);
  float4 b = *(const float4*)(y + (size_t)p1*CDIM + c);
  float4 o4;
  o4.x = w0*a.x + w1*b.x;
  o4.y = w0*a.y + w1*b.y;
  o4.z = w0*a.z + w1*b.z;
  o4.w = w0*a.w + w1*b.w;
  if (fp32f){
    *(float4*)((float*)outv + (size_t)tkn*CDIM + c) = o4;
  } else {
    ushort4 o;
    o.x = f2b(o4.x); o.y = f2b(o4.y); o.z = f2b(o4.z); o.w = f2b(o4.w);
    *(ushort4*)((u16*)outv + (size_t)tkn*CDIM + c) = o;
  }
}

extern "C" void kernel_launch(void* const* d_in, const int* in_sizes, int n_in,
                              void* d_out, int out_size, void* d_ws, size_t ws_size,
                              hipStream_t stream) {
  const void* x  = d_in[0];
  const void* Wr = d_in[1];
  const void* W1 = d_in[2];
  const void* b1 = d_in[3];
  const void* W2 = d_in[4];
  const void* b2 = d_in[5];

  // ws carve (all offsets multiple of 16)
  char* w = (char*)d_ws;
  int*   flagp    = (int*)w;                   // 4 B
  int*   offsets  = (int*)(w + 256);           // 9 ints
  int*   bhist    = (int*)(w + 512);           // 256 ints [512,1536)
  int*   bbase    = (int*)(w + 1536);          // 256 ints [1536,2560)
  int*   tok_e    = (int*)(w + 2560);          // 16384 ints [2560,68096)
  float* tok_w    = (float*)(w + 68096);       // [68096,133632)
  int*   tok_pos  = (int*)(w + 133632);        // [133632,199168)
  int*   pair_tok = (int*)(w + 199168);        // [199168,264704)
  u16*   b1c      = (u16*)(w + 264704);        // 49152 B [264704,313856)
  u16*   b2c      = (u16*)(w + 313856);        // 12288 B [313856,326144)
  u16*   xc       = (u16*)(w + 326144);        // 12582912 B -> 12909056
  u16*   W1t      = (u16*)(w + 12909056);      // [E][H][C] 37748736 B -> 50657792
  u16*   W2t      = W1t + (size_t)NEXP*CDIM*HDIM;      // [E][C][H] 37748736 B -> 88406528
  u16*   h        = W2t + (size_t)NEXP*CDIM*HDIM;      // [NPAIR][H] bf16 -> 189069824
  float* y        = (float*)(h + (size_t)NPAIR*HDIM);  // [NPAIR][C] fp32 -> 239401472
  size_t need = 239401472ull;
  if (ws_size < need) {
    hipMemsetAsync(d_out, 0, (size_t)out_size*2, stream);
    return;
  }

  detect_k<<<1, 256, 0, stream>>>((const u16*)x, flagp);
  conv_k<<<6144, 256, 0, stream>>>(x,  xc,  NTOK*CDIM/4, flagp);
  conv_k<<<24,   256, 0, stream>>>(b1, b1c, NEXP*HDIM/4, flagp);
  conv_k<<<6,    256, 0, stream>>>(b2, b2c, NEXP*CDIM/4, flagp);
  // W1 [E][C][H] -> W1t [E][H][C]; W2 [E][H][C] -> W2t [E][C][H]
  transpose_k<<<dim3(HDIM/64, CDIM/64, NEXP), 256, 0, stream>>>(W1, W1t, CDIM, HDIM, flagp);
  transpose_k<<<dim3(CDIM/64, HDIM/64, NEXP), 256, 0, stream>>>(W2, W2t, HDIM, CDIM, flagp);
  router_k<<<NTOK/4, 256, 0, stream>>>(x, Wr, flagp, tok_e, tok_w);
  hist_k<<<HB, 256, 0, stream>>>(tok_e, bhist);
  offsets2_k<<<1, 64, 0, stream>>>(bhist, offsets, bbase, d_out, flagp);
  scatter2_k<<<HB, 256, 0, stream>>>(tok_e, bbase, pair_tok, tok_pos);
  // GEMM1: h = gelu(x_gathered @ W1[e] + b1[e])   [Me x 3072] bf16
  gemm_k<0,8><<<12288, 256, 0, stream>>>(
      xc, pair_tok, CDIM, W1t, b1c, offsets, CDIM, HDIM, h, nullptr);
  // GEMM2: y = h @ W2[e] + b2[e]                  [Me x 768] fp32
  gemm_k<1,2><<<3072, 256, 0, stream>>>(
      h, nullptr, HDIM, W2t, b2c, offsets, HDIM, CDIM, nullptr, y);
  combine_k<<<NTOK, 192, 0, stream>>>(y, tok_pos, tok_w, d_out, flagp);
}